// Round 5
// baseline (757.320 us; speedup 1.0000x reference)
//
#include <hip/hip_runtime.h>
#include <hip/hip_bf16.h>
#include <stdint.h>

#define NTOK 2048
#define NE 64
#define TOPK 4
#define DM 512
#define DF 2048
#define TOTSLOT (NTOK*TOPK)   // 8192

#define BM 128
#define BN 32
#define BK 64
#define MT 4                  // 4*128 = 512 token capacity per expert (mean 128, sd 11)

typedef __bf16 bf16;
typedef __bf16 bf16x8 __attribute__((ext_vector_type(8)));
typedef __bf16 bf16x4 __attribute__((ext_vector_type(4)));
typedef float  f32x4  __attribute__((ext_vector_type(4)));

#define GLD_LDS16(g, l) __builtin_amdgcn_global_load_lds( \
    (const __attribute__((address_space(1))) void*)(g),   \
    (__attribute__((address_space(3))) void*)(l), 16, 0, 0)
#define WAITV_(N) asm volatile("s_waitcnt vmcnt(" #N ")" ::: "memory")

// ---------------- routing ----------------

__global__ void k_zero(int* counts) { counts[threadIdx.x] = 0; }

__global__ void k_route(const float* __restrict__ hw, float* __restrict__ top_w,
                        int* __restrict__ top_idx, int* __restrict__ counts) {
  int t = blockIdx.x * blockDim.x + threadIdx.x;
  if (t >= NTOK) return;
  const float* r = hw + (size_t)t * NE;
  float rv[NE];
  #pragma unroll
  for (int e = 0; e < NE; ++e) rv[e] = r[e];
  float v[TOPK]; int id[TOPK];
  #pragma unroll
  for (int k = 0; k < TOPK; ++k) {
    float best = -1e30f; int bi = 0;
    #pragma unroll
    for (int e = 0; e < NE; ++e) {
      bool used = false;
      #pragma unroll
      for (int j = 0; j < k; ++j) used |= (id[j] == e);
      if (!used && rv[e] > best) { best = rv[e]; bi = e; }
    }
    v[k] = best; id[k] = bi;
  }
  float den = v[0] + v[1] + v[2] + v[3] + 1e-8f;   // matches ref
  #pragma unroll
  for (int k = 0; k < TOPK; ++k) {
    top_w[t*TOPK + k] = v[k] / den;
    top_idx[t*TOPK + k] = id[k];
    atomicAdd(&counts[id[k]], 1);
  }
}

__global__ void k_scan(const int* __restrict__ counts, int* __restrict__ offsets) {
  if (threadIdx.x == 0) {
    int a = 0;
    for (int e = 0; e < NE; ++e) { offsets[e] = a; a += counts[e]; }
    offsets[NE] = a;
  }
}

// one wave per expert; ballot-ordered deterministic CSR fill
__global__ void k_fill(const int* __restrict__ top_idx, const int* __restrict__ offsets,
                       int* __restrict__ tok, int* __restrict__ slot_of) {
  const int e = blockIdx.x;
  const int lane = threadIdx.x;       // 64
  int pos = offsets[e];
  for (int c = 0; c < TOTSLOT / 64; ++c) {
    int idx = c * 64 + lane;
    bool mine = (top_idx[idx] == e);
    unsigned long long m = __ballot(mine);
    if (mine) {
      int my = __popcll(m & ((1ull << lane) - 1ull));
      tok[pos + my] = idx >> 2;
      slot_of[idx] = pos + my;
    }
    pos += __popcll(m);
  }
}

__global__ void k_xcast(const float* __restrict__ x, bf16* __restrict__ xb) {
  int i = blockIdx.x * blockDim.x + threadIdx.x;
  int base = i * 4;
  if (base >= NTOK * DM) return;
  float4 f = *(const float4*)(x + base);
  bf16x4 o;
  o[0] = (bf16)f.x; o[1] = (bf16)f.y; o[2] = (bf16)f.z; o[3] = (bf16)f.w;
  *(bf16x4*)(xb + base) = o;
}

// -------- grouped GEMM: counted-vmcnt triple-buffered weight streamer --------
// Tile 128(M) x 32(N) x 64(K). 256 threads = 4 waves (2m x 2n), wave tile 64x16.
// ALL staging via global_load_lds (zero VGPR): A bf16 [128][64] (16KB),
// B fp32 [32][64] (8KB). Triple-buffered (72KB -> 2 blocks/CU). Raw s_barrier;
// steady-state s_waitcnt vmcnt(12) keeps 2 tiles (12 loads/wave) in flight --
// the queue NEVER drains. B converted fp32->bf16 after ds_read.
// XOR swizzles (16B units, u ^= row&7) applied on BOTH gload source and
// ds_read (involution, rule 21); bank math: <=2-way (free).
// Grid decode pins expert -> XCD (e = (bx&7)*8 + hi) so m-duplicate weight
// reads and A-panel re-reads across ntiles are L2-local.

template<int PASS>
__global__ __launch_bounds__(256, 2) void k_gemm(
    const float* __restrict__ W, const float* __restrict__ bias,
    const bf16* __restrict__ Asrc, const int* __restrict__ tok,
    const int* __restrict__ offsets,
    bf16* __restrict__ Hout, float* __restrict__ Oout)
{
  constexpr int KFULL = (PASS == 1) ? DM : DF;     // 512 / 2048
  constexpr int NDIM  = (PASS == 1) ? DF : DM;     // 2048 / 512
  constexpr int KT    = KFULL / BK;                // 8 / 32
  constexpr int NT    = NDIM / BN;                 // 64 / 16

  // decode: bx = xcd + 8*(((ehi*NT + ntile)*MT) + mblk)
  const int bx  = blockIdx.x;
  const int xcd = bx & 7;
  const int li  = bx >> 3;
  const int ehi = li / (NT * MT);
  const int rem = li % (NT * MT);
  const int ntile = rem / MT;
  const int mblk  = rem % MT;
  const int e = xcd * 8 + ehi;

  const int off = offsets[e];
  const int cnt = offsets[e+1] - off;
  if (mblk * BM >= cnt) return;                    // block-uniform exit
  const int rowcount = min(cnt - mblk * BM, BM);

  const int tid  = threadIdx.x;
  const int w    = tid >> 6, lane = tid & 63;

  __shared__ bf16  As[3][BM * BK];    // 3 x 16 KB
  __shared__ float Bsf[3][BN * BK];   // 3 x 8 KB

  // ---- A staging map: 4 sweeps x (256 thr x 16B) = 128 rows x 64 k ----
  const int ar = tid >> 3;                     // row within sweep (0..31)
  const int au = (tid & 7) ^ (ar & 7);         // pre-swizzled 16B unit
  const bf16* aptr[4];
  #pragma unroll
  for (int s = 0; s < 4; ++s) {
    int r  = s * 32 + ar;
    int rr = min(r, rowcount - 1);
    int srcrow = (PASS == 1) ? tok[off + mblk*BM + rr] : (off + mblk*BM + rr);
    aptr[s] = Asrc + (size_t)srcrow * KFULL + au * 8;
  }
  // ---- B staging map: 2 sweeps x (256 thr x 16B) = 32 rows x 64 k fp32 ----
  const int brr = tid >> 4;                    // row within sweep (0..15)
  const int bu  = (tid & 15) ^ (brr & 7);      // pre-swizzled 16B unit
  const float* bptr[2];
  #pragma unroll
  for (int s = 0; s < 2; ++s)
    bptr[s] = W + ((size_t)e * NDIM + ntile*BN + s*16 + brr) * KFULL + bu * 4;

  char* const abase = (char*)&As[0][0];
  char* const bbase = (char*)&Bsf[0][0];

  auto STAGE = [&](int kt, int b) {
    #pragma unroll
    for (int s = 0; s < 4; ++s)
      GLD_LDS16(aptr[s] + kt*BK, abase + b*16384 + s*4096 + w*1024);
    #pragma unroll
    for (int s = 0; s < 2; ++s)
      GLD_LDS16(bptr[s] + kt*BK, bbase + b*8192 + s*4096 + w*1024);
  };

  // ---- fragment geometry ----
  const int wm = w >> 1, wn = w & 1;
  const int lcol = lane & 15, lrow = lane >> 4;

  f32x4 acc[4] = {};

  auto compute = [&](int b) {
    #pragma unroll
    for (int ks = 0; ks < 2; ++ks) {
      const int uu = ks*4 + lrow;
      const int n  = wn*16 + lcol;
      const float* Bb = &Bsf[b][n * BK];
      float4 x0 = *(const float4*)(Bb + (((uu*2    ) ^ (n & 7)) * 4));
      float4 x1 = *(const float4*)(Bb + (((uu*2 + 1) ^ (n & 7)) * 4));
      bf16x8 bf;
      bf[0]=(bf16)x0.x; bf[1]=(bf16)x0.y; bf[2]=(bf16)x0.z; bf[3]=(bf16)x0.w;
      bf[4]=(bf16)x1.x; bf[5]=(bf16)x1.y; bf[6]=(bf16)x1.z; bf[7]=(bf16)x1.w;
      #pragma unroll
      for (int i = 0; i < 4; ++i) {
        int m = wm*64 + i*16 + lcol;
        bf16x8 af = *(const bf16x8*)(&As[b][m*BK + ((uu ^ (m & 7)) * 8)]);
        acc[i] = __builtin_amdgcn_mfma_f32_16x16x32_bf16(af, bf, acc[i], 0, 0, 0);
      }
    }
  };

  // ---- prologue: tiles 0,1 in flight; wait tile 0 only ----
  STAGE(0, 0);
  STAGE(1, 1);
  WAITV_(6);
  __builtin_amdgcn_s_barrier();

  int b0 = 0;
  #pragma unroll 1
  for (int kt = 0; kt < KT; ++kt) {
    __builtin_amdgcn_s_barrier();            // all done reading tile kt-1
    __builtin_amdgcn_sched_barrier(0);
    if (kt + 2 < KT) {
      int bs = (b0 + 2 >= 3) ? b0 - 1 : b0 + 2;
      STAGE(kt + 2, bs);                     // into buffer freed above
      WAITV_(12);                            // my tile-kt loads done; 2 tiles stay in flight
    } else if (kt + 1 < KT) {
      WAITV_(6);
    } else {
      WAITV_(0);
    }
    __builtin_amdgcn_s_barrier();            // everyone's tile kt landed
    __builtin_amdgcn_sched_barrier(0);
    compute(b0);
    b0 = (b0 == 2) ? 0 : b0 + 1;
  }

  // ---- epilogue. C/D: col = lane&15 (n), row = lrow*4 + q (m) ----
  const int slotbase = off + mblk * BM;
  const int gcol = ntile*BN + wn*16 + lcol;
  const float bv = bias[(size_t)e * NDIM + gcol];
  #pragma unroll
  for (int i = 0; i < 4; ++i) {
    const int rb2 = wm*64 + i*16 + lrow*4;
    #pragma unroll
    for (int q = 0; q < 4; ++q) {
      const int r = rb2 + q;
      if (r < rowcount) {
        float h = acc[i][q] + bv;
        if (PASS == 1) {
          float s = h / (1.0f + __expf(-h));      // silu
          Hout[(size_t)(slotbase + r) * DF + gcol] = (bf16)s;
        } else {
          Oout[(size_t)(slotbase + r) * DM + gcol] = h;
        }
      }
    }
  }
}

// ---------------- combine (deterministic, atomic-free) ----------------

__global__ void k_combine(const float* __restrict__ O, const float* __restrict__ top_w,
                          const int* __restrict__ slot_of, float* __restrict__ out) {
  int i = blockIdx.x * blockDim.x + threadIdx.x;
  if (i >= NTOK * DM / 4) return;
  int t  = i / (DM / 4);
  int d4 = (i % (DM / 4)) * 4;
  float4 s = {0.f, 0.f, 0.f, 0.f};
  #pragma unroll
  for (int k = 0; k < TOPK; ++k) {
    float w = top_w[t*TOPK + k];
    int  sl = slot_of[t*TOPK + k];
    float4 o = *(const float4*)(O + (size_t)sl * DM + d4);
    s.x += w * o.x; s.y += w * o.y; s.z += w * o.z; s.w += w * o.w;
  }
  *(float4*)(out + (size_t)t * DM + d4) = s;
}

// ---------------- launch ----------------

extern "C" void kernel_launch(void* const* d_in, const int* in_sizes, int n_in,
                              void* d_out, int out_size, void* d_ws, size_t ws_size,
                              hipStream_t stream) {
  const float* x        = (const float*)d_in[0];
  const float* hw       = (const float*)d_in[1];
  const float* W_in     = (const float*)d_in[2];
  const float* bias_in  = (const float*)d_in[3];
  const float* W_out    = (const float*)d_in[4];
  const float* bias_out = (const float*)d_in[5];
  float* out = (float*)d_out;

  char* ws = (char*)d_ws;
  int*   counts  = (int*)  (ws + 0);                     // 64 ints
  int*   offsets = (int*)  (ws + 512);                   // 65 ints
  int*   top_idx = (int*)  (ws + 1024);                  // 32 KB
  float* top_w   = (float*)(ws + 1024 + 32768);          // 32 KB
  int*   slot_of = (int*)  (ws + 1024 + 2*32768);        // 32 KB
  int*   tok     = (int*)  (ws + 1024 + 3*32768);        // 32 KB
  bf16*  xb      = (bf16*) (ws + 1024 + 4*32768);        // 2 MB
  size_t o_xb_end = 1024 + 4*32768 + (size_t)NTOK*DM*2;
  bf16*  H       = (bf16*) (ws + o_xb_end);              // 32 MB
  size_t o_H_end  = o_xb_end + (size_t)TOTSLOT*DF*2;
  float* O       = (float*)(ws + o_H_end);               // 16 MB

  k_zero <<<1, NE, 0, stream>>>(counts);
  k_route<<<NTOK/256, 256, 0, stream>>>(hw, top_w, top_idx, counts);
  k_scan <<<1, 64, 0, stream>>>(counts, offsets);
  k_fill <<<NE, 64, 0, stream>>>(top_idx, offsets, tok, slot_of);
  k_xcast<<<(NTOK*DM/4)/256, 256, 0, stream>>>(x, xb);

  // grid.x = 8 xcd * 8 ehi * NT * MT
  k_gemm<1><<<64 * (DF/BN) * MT, 256, 0, stream>>>(W_in, bias_in, xb, tok, offsets, H, nullptr);
  k_gemm<2><<<64 * (DM/BN) * MT, 256, 0, stream>>>(W_out, bias_out, H, nullptr, offsets, nullptr, O);

  k_combine<<<(NTOK*DM/4)/256, 256, 0, stream>>>(O, top_w, slot_of, out);
}

// Round 6
// 272.722 us; speedup vs baseline: 2.7769x; 2.7769x over previous
//
#include <hip/hip_runtime.h>
#include <hip/hip_bf16.h>
#include <stdint.h>

#define NTOK 2048
#define NE 64
#define TOPK 4
#define DM 512
#define DF 2048
#define TOTSLOT (NTOK*TOPK)   // 8192

// GEMM tile config: one 192-row M-tile per expert covers counts up to 192
// (mean 128, sigma ~11). Worst case handled by MT_MAX tiles w/ early exit.
#define BM 192
#define BN 128
#define BK 64
#define MT_MAX 11             // ceil(2048/192)

typedef __bf16 bf16;
typedef __bf16 bf16x8 __attribute__((ext_vector_type(8)));
typedef __bf16 bf16x4 __attribute__((ext_vector_type(4)));
typedef float  f32x4  __attribute__((ext_vector_type(4)));
typedef short  short8 __attribute__((ext_vector_type(8)));

// ---------------- routing (4 cheap parallel kernels) ----------------

__global__ void k_zero(int* counts) { counts[threadIdx.x] = 0; }

__global__ void k_route(const float* __restrict__ hw, float* __restrict__ top_w,
                        int* __restrict__ top_idx, int* __restrict__ counts) {
  int t = blockIdx.x * blockDim.x + threadIdx.x;
  if (t >= NTOK) return;
  const float* r = hw + (size_t)t * NE;
  float rv[NE];
  #pragma unroll
  for (int e = 0; e < NE; ++e) rv[e] = r[e];
  float v[TOPK]; int id[TOPK];
  #pragma unroll
  for (int k = 0; k < TOPK; ++k) {
    float best = -1e30f; int bi = 0;
    #pragma unroll
    for (int e = 0; e < NE; ++e) {
      bool used = false;
      #pragma unroll
      for (int j = 0; j < k; ++j) used |= (id[j] == e);
      if (!used && rv[e] > best) { best = rv[e]; bi = e; }
    }
    v[k] = best; id[k] = bi;
  }
  float den = v[0] + v[1] + v[2] + v[3] + 1e-8f;   // matches ref
  #pragma unroll
  for (int k = 0; k < TOPK; ++k) {
    top_w[t*TOPK + k] = v[k] / den;
    top_idx[t*TOPK + k] = id[k];
    atomicAdd(&counts[id[k]], 1);
  }
}

__global__ void k_scan(const int* __restrict__ counts, int* __restrict__ offsets) {
  if (threadIdx.x == 0) {
    int a = 0;
    for (int e = 0; e < NE; ++e) { offsets[e] = a; a += counts[e]; }
    offsets[NE] = a;
  }
}

// one wave per expert; ballot-ordered deterministic CSR fill
__global__ void k_fill(const int* __restrict__ top_idx, const int* __restrict__ offsets,
                       int* __restrict__ tok, int* __restrict__ slot_of) {
  const int e = blockIdx.x;
  const int lane = threadIdx.x;       // 64
  int pos = offsets[e];
  for (int c = 0; c < TOTSLOT / 64; ++c) {
    int idx = c * 64 + lane;
    bool mine = (top_idx[idx] == e);
    unsigned long long m = __ballot(mine);
    if (mine) {
      int my = __popcll(m & ((1ull << lane) - 1ull));
      tok[pos + my] = idx >> 2;       // token = idx / TOPK
      slot_of[idx] = pos + my;
    }
    pos += __popcll(m);
  }
}

__global__ void k_xcast(const float* __restrict__ x, bf16* __restrict__ xb) {
  int i = blockIdx.x * blockDim.x + threadIdx.x;
  int base = i * 4;
  if (base >= NTOK * DM) return;
  float4 f = *(const float4*)(x + base);
  bf16x4 o;
  o[0] = (bf16)f.x; o[1] = (bf16)f.y; o[2] = (bf16)f.z; o[3] = (bf16)f.w;
  *(bf16x4*)(xb + base) = o;
}

// ---------------- grouped GEMM (R1 structure: simple 2-barrier loop) ----------------
// PASS 1: A = gathered x_bf16 rows (CSR), B^T = W_in[e] (F x D fp32), K=DM,
//         epilogue silu(acc+bias_in) -> H bf16.  KSPLIT=1.
// PASS 2: A = H rows (contiguous slots), B^T = W_out[e] (D x F fp32), KSPLIT=2
//         (KLOC=1024) -> 512 real blocks = 2-3 blocks/CU so the per-tile
//         barrier drain is covered by co-resident blocks (m114 overlap).
//         Partial O buffers per ks; bias added by ks==0; combine sums.
// LDS layout: [row][64 cols] bf16 with 16B-unit XOR swizzle (unit ^= row&7).

template<int PASS, int KSPLIT>
__global__ __launch_bounds__(512) void k_gemm(
    const float* __restrict__ W, const float* __restrict__ bias,
    const bf16* __restrict__ Asrc, const int* __restrict__ tok,
    const int* __restrict__ offsets,
    bf16* __restrict__ Hout, float* __restrict__ Oout)
{
  constexpr int KFULL = (PASS == 1) ? DM : DF;
  constexpr int KLOC  = KFULL / KSPLIT;
  constexpr int KT    = KLOC / BK;
  constexpr int NDIM  = (PASS == 1) ? DF : DM;

  const int e     = blockIdx.z;
  const int mtile = blockIdx.y;
  const int bx    = blockIdx.x;
  const int ntile = bx / KSPLIT;
  const int ks    = bx % KSPLIT;
  const int kbase = ks * KLOC;

  const int off   = offsets[e];
  const int cnt   = offsets[e+1] - off;
  if (mtile * BM >= cnt) return;            // early-exit: uniform per block
  const int rowcount = cnt - mtile * BM;    // only r<rowcount valid
  const int tid = threadIdx.x;

  __shared__ bf16 As[BM * BK];   // 24 KB
  __shared__ bf16 Bs[BN * BK];   // 16 KB

  // --- A staging map: 3 chunks x (512 thr x 8 bf16) covers 192x64 ---
  const bf16* abase[3]; bool aok[3];
  #pragma unroll
  for (int c = 0; c < 3; ++c) {
    int r = (c * 512 + tid) >> 3;           // row in tile 0..191
    aok[c] = (r < rowcount);
    int srcrow;
    if (PASS == 1) srcrow = aok[c] ? tok[off + mtile*BM + r] : 0;
    else           srcrow = min(off + mtile*BM + r, TOTSLOT - 1);
    abase[c] = Asrc + (size_t)srcrow * KFULL + kbase + (tid & 7) * 8;
  }
  // --- B staging map: thread -> (row = tid>>2, 16-col segment) ---
  const int brow = tid >> 2;
  const float* bbase = W + (size_t)e * NDIM * KFULL
                         + (size_t)(ntile*BN + brow) * KFULL + kbase + (tid & 3) * 16;

  // --- wave / fragment geometry: 8 waves = 4(M) x 2(N), wave tile 48x64 ---
  const int wave = tid >> 6, lane = tid & 63;
  const int wm = wave >> 1, wn = wave & 1;
  const int lrow = lane >> 4, lcol = lane & 15;

  f32x4 acc[3][4];
  #pragma unroll
  for (int i = 0; i < 3; ++i)
    #pragma unroll
    for (int j = 0; j < 4; ++j) acc[i][j] = (f32x4)(0.0f);

  #pragma unroll 1
  for (int kt = 0; kt < KT; ++kt) {
    const int k0 = kt * BK;
    // load A (bf16, 16B/lane) and B (fp32, 4x float4/lane) to regs
    short8 areg[3];
    #pragma unroll
    for (int c = 0; c < 3; ++c) {
      if (PASS == 2 || aok[c]) areg[c] = *(const short8*)(abase[c] + k0);
      else                     areg[c] = (short8){0,0,0,0,0,0,0,0};
    }
    float4 breg[4];
    #pragma unroll
    for (int q = 0; q < 4; ++q) breg[q] = *(const float4*)(bbase + k0 + q*4);

    __syncthreads();   // previous tile fully consumed
    // write A (swizzled 16B units)
    #pragma unroll
    for (int c = 0; c < 3; ++c) {
      int r = (c * 512 + tid) >> 3;
      int u = tid & 7;
      *(short8*)(&As[r*BK + ((u ^ (r & 7)) * 8)]) = areg[c];
    }
    // convert + write B (fp32 -> bf16, two swizzled 16B units)
    {
      const float* fv = (const float*)breg;
      bf16x8 p0, p1;
      #pragma unroll
      for (int q = 0; q < 8; ++q) { p0[q] = (bf16)fv[q]; p1[q] = (bf16)fv[q+8]; }
      int u0 = (tid & 3) * 2;
      *(bf16x8*)(&Bs[brow*BK + (((u0  ) ^ (brow & 7)) * 8)]) = p0;
      *(bf16x8*)(&Bs[brow*BK + (((u0+1) ^ (brow & 7)) * 8)]) = p1;
    }
    __syncthreads();   // staging visible

    // compute: 2 MFMA K-subtiles of 32
    #pragma unroll
    for (int ksub = 0; ksub < 2; ++ksub) {
      const int uu = ksub*4 + lrow;
      bf16x8 af[3], bfr[4];
      #pragma unroll
      for (int i = 0; i < 3; ++i) {
        int m = wm*48 + i*16 + lcol;
        af[i] = *(const bf16x8*)(&As[m*BK + ((uu ^ (m & 7)) * 8)]);
      }
      #pragma unroll
      for (int j = 0; j < 4; ++j) {
        int n = wn*64 + j*16 + lcol;
        bfr[j] = *(const bf16x8*)(&Bs[n*BK + ((uu ^ (n & 7)) * 8)]);
      }
      #pragma unroll
      for (int i = 0; i < 3; ++i)
        #pragma unroll
        for (int j = 0; j < 4; ++j)
          acc[i][j] = __builtin_amdgcn_mfma_f32_16x16x32_bf16(af[i], bfr[j], acc[i][j], 0, 0, 0);
    }
  }

  // --- epilogue. C/D layout: col = lane&15, row = (lane>>4)*4 + reg ---
  const int slotbase = off + mtile * BM;
  #pragma unroll
  for (int i = 0; i < 3; ++i) {
    const int rbase = wm*48 + i*16 + lrow*4;
    #pragma unroll
    for (int j = 0; j < 4; ++j) {
      const int gcol = ntile*BN + wn*64 + j*16 + lcol;
      const float bv = (PASS == 2 && ks != 0) ? 0.0f : bias[(size_t)e * NDIM + gcol];
      #pragma unroll
      for (int q = 0; q < 4; ++q) {
        const int r = rbase + q;
        if (r < rowcount) {
          float h = acc[i][j][q] + bv;
          if (PASS == 1) {
            float s = h / (1.0f + __expf(-h));      // silu
            Hout[(size_t)(slotbase + r) * DF + gcol] = (bf16)s;
          } else {
            Oout[(size_t)ks * TOTSLOT * DM + (size_t)(slotbase + r) * DM + gcol] = h;
          }
        }
      }
    }
  }
}

// ---------------- combine (deterministic, sums K-split partials) ----------------

__global__ void k_combine(const float* __restrict__ O, const float* __restrict__ top_w,
                          const int* __restrict__ slot_of, float* __restrict__ out) {
  int i = blockIdx.x * blockDim.x + threadIdx.x;
  if (i >= NTOK * DM / 4) return;
  int t  = i / (DM / 4);
  int d4 = (i % (DM / 4)) * 4;
  float4 s = {0.f, 0.f, 0.f, 0.f};
  #pragma unroll
  for (int k = 0; k < TOPK; ++k) {
    float w = top_w[t*TOPK + k];
    int  sl = slot_of[t*TOPK + k];
    float4 o0 = *(const float4*)(O + (size_t)sl * DM + d4);
    float4 o1 = *(const float4*)(O + (size_t)TOTSLOT * DM + (size_t)sl * DM + d4);
    s.x += w * (o0.x + o1.x); s.y += w * (o0.y + o1.y);
    s.z += w * (o0.z + o1.z); s.w += w * (o0.w + o1.w);
  }
  *(float4*)(out + (size_t)t * DM + d4) = s;
}

// ---------------- launch ----------------

extern "C" void kernel_launch(void* const* d_in, const int* in_sizes, int n_in,
                              void* d_out, int out_size, void* d_ws, size_t ws_size,
                              hipStream_t stream) {
  const float* x        = (const float*)d_in[0];
  const float* hw       = (const float*)d_in[1];
  const float* W_in     = (const float*)d_in[2];
  const float* bias_in  = (const float*)d_in[3];
  const float* W_out    = (const float*)d_in[4];
  const float* bias_out = (const float*)d_in[5];
  float* out = (float*)d_out;

  char* ws = (char*)d_ws;
  int*   counts  = (int*)  (ws + 0);                     // 64 ints
  int*   offsets = (int*)  (ws + 512);                   // 65 ints
  int*   top_idx = (int*)  (ws + 1024);                  // 32 KB
  float* top_w   = (float*)(ws + 1024 + 32768);          // 32 KB
  int*   slot_of = (int*)  (ws + 1024 + 2*32768);        // 32 KB
  int*   tok     = (int*)  (ws + 1024 + 3*32768);        // 32 KB
  bf16*  xb      = (bf16*) (ws + 1024 + 4*32768);        // 2 MB
  size_t o_xb_end = 1024 + 4*32768 + (size_t)NTOK*DM*2;
  bf16*  H       = (bf16*) (ws + o_xb_end);              // 32 MB
  size_t o_H_end  = o_xb_end + (size_t)TOTSLOT*DF*2;
  float* O       = (float*)(ws + o_H_end);               // 2 x 16 MB partials

  k_zero <<<1, NE, 0, stream>>>(counts);
  k_route<<<NTOK/256, 256, 0, stream>>>(hw, top_w, top_idx, counts);
  k_scan <<<1, 64, 0, stream>>>(counts, offsets);
  k_fill <<<NE, 64, 0, stream>>>(top_idx, offsets, tok, slot_of);
  k_xcast<<<(NTOK*DM/4)/256, 256, 0, stream>>>(x, xb);

  dim3 g1(DF/BN, MT_MAX, NE);         // (16, 11, 64), KSPLIT=1
  k_gemm<1,1><<<g1, 512, 0, stream>>>(W_in, bias_in, xb, tok, offsets, H, nullptr);
  dim3 g2((DM/BN)*2, MT_MAX, NE);     // (8, 11, 64), KSPLIT=2
  k_gemm<2,2><<<g2, 512, 0, stream>>>(W_out, bias_out, H, nullptr, offsets, nullptr, O);

  k_combine<<<(NTOK*DM/4)/256, 256, 0, stream>>>(O, top_w, slot_of, out);
}